// Round 3
// baseline (751.095 us; speedup 1.0000x reference)
//
#include <hip/hip_runtime.h>

#define LOG2E 1.4426950408889634f
#define TWO_LOG2E 2.8853900817779268f

#if __has_builtin(__builtin_amdgcn_exp2f)
__device__ __forceinline__ float fexp2(float x){ return __builtin_amdgcn_exp2f(x); }
#else
__device__ __forceinline__ float fexp2(float x){ return exp2f(x); }
#endif
#if __has_builtin(__builtin_amdgcn_rcpf)
__device__ __forceinline__ float frcp(float x){ return __builtin_amdgcn_rcpf(x); }
#else
__device__ __forceinline__ float frcp(float x){ return 1.0f/(x); }
#endif

// DPP cross-lane move (full-rate VALU, no LDS pipe)
template<int CTRL>
__device__ __forceinline__ float dpp_f(float x) {
    return __int_as_float(__builtin_amdgcn_update_dpp(0, __float_as_int(x), CTRL, 0xF, 0xF, true));
}
#define DPP_XOR1  0xB1   // quad_perm(1,0,3,2)
#define DPP_XOR2  0x4E   // quad_perm(2,3,0,1)
#define DPP_BC0   0x00   // quad bcast lane0
#define DPP_BC1   0x55
#define DPP_BC2   0xAA
#define DPP_BC3   0xFF

typedef unsigned int u32;
typedef _Float16 h2 __attribute__((ext_vector_type(2)));

__device__ __forceinline__ h2 ash2(u32 x){ return __builtin_bit_cast(h2, x); }

// pack two fp32 -> 2x fp16 (RTN via scalar cvt)
__device__ __forceinline__ u32 pkh(float x, float y) {
    union { u32 u; _Float16 f[2]; } r;
    r.f[0] = (_Float16)x; r.f[1] = (_Float16)y;
    return r.u;
}

// ---- layer-0 pre GEMM with fused embedding gather + csum zeroing ----------
__global__ __launch_bounds__(256) void gemm_l0(
    const int* __restrict__ wid, const int* __restrict__ tgi,
    const float* __restrict__ wemb, const float* __restrict__ temb,
    const float* __restrict__ Wa, const float* __restrict__ Wb,
    const float* __restrict__ b1a, const float* __restrict__ b1b,
    const float* __restrict__ b2a, const float* __restrict__ b2b,
    float* __restrict__ Ca, float* __restrict__ Cb,
    float* __restrict__ csum)
{
    int tid = threadIdx.x;
    if (blockIdx.x == 0 && blockIdx.y == 0 && blockIdx.z == 0) {
        csum[tid] = 0.f; csum[tid + 256] = 0.f;   // zero for score's atomics
    }
    int z = blockIdx.z;
    const float* W   = z ? Wb  : Wa;
    const float* bb1 = z ? b1b : b1a;
    const float* bb2 = z ? b2b : b2a;
    float* C = z ? Cb : Ca;

    __shared__ float Xs[64*33];
    __shared__ float Ws[64*33];
    int tx = tid & 15, ty = tid >> 4;
    int n0 = blockIdx.y*64, r0 = blockIdx.x*64;
    float acc[4][4] = {};

    for (int k0 = 0; k0 < 128; k0 += 32) {
        #pragma unroll
        for (int i = 0; i < 2; ++i) {
            int idx = tid + 256*i;
            int row = idx >> 3, c4 = idx & 7;
            int k = k0 + c4*4;
            int rg = n0 + row;
            float4 vx = (k < 100) ? *(const float4*)(wemb + wid[rg]*100 + k)
                                  : *(const float4*)(temb + tgi[rg]*28 + (k-100));
            float4 vw = *(const float4*)(W + (r0+row)*128 + k0 + c4*4);
            Xs[row*33 + c4*4+0]=vx.x; Xs[row*33 + c4*4+1]=vx.y; Xs[row*33 + c4*4+2]=vx.z; Xs[row*33 + c4*4+3]=vx.w;
            Ws[row*33 + c4*4+0]=vw.x; Ws[row*33 + c4*4+1]=vw.y; Ws[row*33 + c4*4+2]=vw.z; Ws[row*33 + c4*4+3]=vw.w;
        }
        __syncthreads();
        #pragma unroll 8
        for (int kk = 0; kk < 32; ++kk) {
            float a[4], b[4];
            #pragma unroll
            for (int i = 0; i < 4; ++i) a[i] = Xs[(4*ty+i)*33 + kk];
            #pragma unroll
            for (int j = 0; j < 4; ++j) b[j] = Ws[(4*tx+j)*33 + kk];
            #pragma unroll
            for (int i = 0; i < 4; ++i)
                #pragma unroll
                for (int j = 0; j < 4; ++j)
                    acc[i][j] = fmaf(a[i], b[j], acc[i][j]);
        }
        __syncthreads();
    }
    #pragma unroll
    for (int i = 0; i < 4; ++i)
        #pragma unroll
        for (int j = 0; j < 4; ++j) {
            int r = r0 + 4*tx + j;
            C[(n0 + 4*ty + i)*512 + r] = acc[i][j] + bb1[r] + bb2[r];
        }
}

// ------------- generic fused-pair GEMM: C[n][r] = scale*(X·W^T + b1 + b2) ----
__global__ __launch_bounds__(256) void gemm2(
    const float* __restrict__ X, int ldx,
    const float* __restrict__ Wa, const float* __restrict__ Wb, int ldw, int woffb,
    const float* __restrict__ b1a, const float* __restrict__ b1b,
    const float* __restrict__ b2a, const float* __restrict__ b2b,
    float* __restrict__ Ca, float* __restrict__ Cb,
    int K, float scale)
{
    int z = blockIdx.z;
    const float* W  = z ? Wb  : Wa;
    const float* bb1 = z ? b1b : b1a;
    const float* bb2 = z ? b2b : b2a;
    float* C = z ? Cb : Ca;
    int woff = z ? woffb : 0;

    __shared__ float Xs[64*33];
    __shared__ float Ws[64*33];
    int tid = threadIdx.x;
    int tx = tid & 15, ty = tid >> 4;
    int n0 = blockIdx.y*64, r0 = blockIdx.x*64;
    float acc[4][4] = {};

    for (int k0 = 0; k0 < K; k0 += 32) {
        #pragma unroll
        for (int i = 0; i < 2; ++i) {
            int idx = tid + 256*i;
            int row = idx >> 3, c4 = idx & 7;
            float4 vx = *(const float4*)(X + (n0+row)*ldx + k0 + c4*4);
            float4 vw = *(const float4*)(W + (r0+row)*ldw + woff + k0 + c4*4);
            Xs[row*33 + c4*4+0]=vx.x; Xs[row*33 + c4*4+1]=vx.y; Xs[row*33 + c4*4+2]=vx.z; Xs[row*33 + c4*4+3]=vx.w;
            Ws[row*33 + c4*4+0]=vw.x; Ws[row*33 + c4*4+1]=vw.y; Ws[row*33 + c4*4+2]=vw.z; Ws[row*33 + c4*4+3]=vw.w;
        }
        __syncthreads();
        #pragma unroll 8
        for (int kk = 0; kk < 32; ++kk) {
            float a[4], b[4];
            #pragma unroll
            for (int i = 0; i < 4; ++i) a[i] = Xs[(4*ty+i)*33 + kk];
            #pragma unroll
            for (int j = 0; j < 4; ++j) b[j] = Ws[(4*tx+j)*33 + kk];
            #pragma unroll
            for (int i = 0; i < 4; ++i)
                #pragma unroll
                for (int j = 0; j < 4; ++j)
                    acc[i][j] = fmaf(a[i], b[j], acc[i][j]);
        }
        __syncthreads();
    }
    #pragma unroll
    for (int i = 0; i < 4; ++i)
        #pragma unroll
        for (int j = 0; j < 4; ++j) {
            int r = r0 + 4*tx + j;
            float v = acc[i][j];
            if (bb1) v += bb1[r];
            if (bb2) v += bb2[r];
            C[(n0 + 4*ty + i)*512 + r] = v*scale;
        }
}

// ---------------- LSTM: 512 threads, packed-fp16 recurrent MAC --------------
// lane: sub = tid&3 (col slice of 32 cols), cell j = tid>>2, owns all 4
// gate-rows of cell j over its 32 cols. MAC via v_pk_fma_f16 (full-rate
// VOP3P, 2 MACs/2cy — v_dot2_f32_f16 measured half-rate on gfx950, R2).
// Two packed accumulators per row = four 8-deep fp16 chains; combined via
// pk_add + 2 cvt at the end. Barrier = lgkmcnt-only (R2). Transpose-butterfly
// reduce leaves each lane holding exactly its gate.
__global__ __launch_bounds__(512, 2) void lstm_kernel(
    const float* __restrict__ preF, const float* __restrict__ preB,
    const float* __restrict__ WhhF, const float* __restrict__ WhhB,
    const float* __restrict__ h0, const float* __restrict__ c0,
    float* __restrict__ hout, int layer)
{
    const int dir = blockIdx.x;
    const int tid = threadIdx.x;
    const int sub = tid & 3;        // col slice 0..3
    const int j   = tid >> 2;       // cell 0..127
    const int q   = sub;            // gate handled by this lane's transcendental
    const float* Whh  = dir ? WhhB : WhhF;
    const float* preD = dir ? preB : preF;

    // chunk schedule: instr k -> absolute 16B chunk (8 fp16 cols) cid[k] in
    // [4sub, 4sub+4). At each k the 4 subs hit 4 disjoint 4-bank groups;
    // 16 cells broadcast the same address (free).
    int cid[4];
    #pragma unroll
    for (int k = 0; k < 4; ++k) cid[k] = (sub << 2) + ((k + sub) & 3);

    // fp16 weights (VGPR-resident, VOP3P-sourceable):
    // w2[r][4k+m] packs Whh[(r<<7)+j][8*cid[k]+2m .. +1]
    u32 w2[4][16];
    #pragma unroll
    for (int r = 0; r < 4; ++r) {
        const float* wr = Whh + ((r << 7) + j)*128;
        #pragma unroll
        for (int k = 0; k < 4; ++k) {
            float4 v0 = *(const float4*)(wr + 8*cid[k]);
            float4 v1 = *(const float4*)(wr + 8*cid[k] + 4);
            w2[r][4*k+0] = pkh(v0.x, v0.y);
            w2[r][4*k+1] = pkh(v0.z, v0.w);
            w2[r][4*k+2] = pkh(v1.x, v1.y);
            w2[r][4*k+3] = pkh(v1.z, v1.w);
        }
    }

    __shared__ __align__(16) _Float16 hbuf[2][128];   // fp16 h ping-pong

    const float* h0d = h0 + (2*layer + dir)*128;
    const float* c0d = c0 + (2*layer + dir)*128;
    float c = c0d[j];
    if (tid < 128) hbuf[0][tid] = (_Float16)h0d[tid];

    const float sc = (q == 2) ? -TWO_LOG2E : -LOG2E;   // gate 2: sigm(2*gg)
    const int prow = (q << 7) + j;
    const int t0 = dir ? 511 : 0;
    const int dt = dir ? -1 : 1;
    const int pstep = dt*512;
    const int hstep = dt*256;

    // pointer-walking; the one-past-the-end prefetch on the last step lands
    // in the adjacent workspace region (pA<->pB) — in bounds, value unused.
    const float* pptr = preD + t0*512 + prow;
    float*       hptr = hout + t0*256 + dir*128 + j;

    float pcur = *pptr;
    __syncthreads();

    #pragma unroll 2
    for (int s = 0; s < 512; ++s) {
        pptr += pstep;
        float pnext = *pptr;           // prefetch one step ahead

        const int p = s & 1;
        const uint4* h4 = (const uint4*)hbuf[p];
        uint4 hv[4];
        #pragma unroll
        for (int k = 0; k < 4; ++k) hv[k] = h4[cid[k]];

        // packed fp16 MAC: four 8-deep chains per gate-row (v_pk_fma_f16)
        h2 accA[4], accB[4];
        #pragma unroll
        for (int r = 0; r < 4; ++r) { accA[r] = (h2)(_Float16)0; accB[r] = (h2)(_Float16)0; }
        #pragma unroll
        for (int k = 0; k < 4; ++k) {
            h2 hx = ash2(hv[k].x), hy = ash2(hv[k].y);
            h2 hz = ash2(hv[k].z), hw = ash2(hv[k].w);
            #pragma unroll
            for (int r = 0; r < 4; ++r) {
                accA[r] += ash2(w2[r][4*k+0]) * hx;
                accB[r] += ash2(w2[r][4*k+1]) * hy;
                accA[r] += ash2(w2[r][4*k+2]) * hz;
                accB[r] += ash2(w2[r][4*k+3]) * hw;
            }
        }
        float acc[4];
        #pragma unroll
        for (int r = 0; r < 4; ++r) {
            h2 sσ = accA[r] + accB[r];            // v_pk_add_f16
            acc[r] = (float)sσ.x + (float)sσ.y;   // 2 cvt + add
        }

        // transpose-butterfly: lane sub ends holding the full sum for gate sub.
        float y0 = (q & 1) ? acc[1] : acc[0];
        float z0 = (q & 1) ? acc[0] : acc[1];
        float w0 = y0 + dpp_f<DPP_XOR1>(z0);     // gate (q&1), slices pair
        float y2 = (q & 1) ? acc[3] : acc[2];
        float z2 = (q & 1) ? acc[2] : acc[3];
        float wv = y2 + dpp_f<DPP_XOR1>(z2);     // gate (q&1)+2, slices pair
        float u  = (q & 2) ? wv : w0;
        float v  = (q & 2) ? w0 : wv;
        float g  = u + dpp_f<DPP_XOR2>(v);       // gate q, all 4 slices

        float xg  = (g + pcur) * sc;
        float sv  = frcp(1.f + fexp2(xg));

        // share the four gates within the quad
        float vi = dpp_f<DPP_BC0>(sv);
        float vf = dpp_f<DPP_BC1>(sv);
        float vg = dpp_f<DPP_BC2>(sv);
        float vo = dpp_f<DPP_BC3>(sv);

        float tg = fmaf(2.f, vg, -1.f);           // tanh(gg)
        c = fmaf(vf, c, vi*tg);
        float th = fmaf(-2.f, frcp(1.f + fexp2(TWO_LOG2E*c)), 1.f);  // tanh(c)
        float h  = vo * th;

        if (sub == 1) hbuf[p ^ 1][j] = (_Float16)h;
        if (sub == 2) *hptr = h;
        hptr += hstep;
        // LDS-only barrier: do NOT drain vmcnt (hout store + pre prefetch
        // retire via the in-order vmcnt queue one step later, off-path).
        asm volatile("s_waitcnt lgkmcnt(0)\n\ts_barrier" ::: "memory");
        pcur = pnext;
    }
}

// --------- score: S[n][m] = sum_h w2[h]*tanh(A+B+b1) + b2, diag=0 -----------
__global__ __launch_bounds__(256) void score_kernel(
    const float* __restrict__ Ap, const float* __restrict__ Bp,
    const float* __restrict__ W2, const float* __restrict__ b2p,
    float* __restrict__ S, float* __restrict__ csum)
{
    __shared__ __align__(16) float As[32*132];
    __shared__ __align__(16) float Bs[16*132];
    __shared__ __align__(16) float W2s[128];
    __shared__ float ps[16][17];
    int tid = threadIdx.x;
    int tx = tid & 15, ty = tid >> 4;
    int m0 = blockIdx.x*16, n0 = blockIdx.y*32;
    float acc0 = 0.f, acc1 = 0.f;

    for (int hc = 0; hc < 512; hc += 128) {
        #pragma unroll
        for (int i = 0; i < 4; ++i) {
            int idx = tid + 256*i;
            int row = idx >> 5, c4 = idx & 31;
            *(float4*)&As[row*132 + c4*4] = *(const float4*)(Ap + (n0+row)*512 + hc + c4*4);
        }
        #pragma unroll
        for (int i = 0; i < 2; ++i) {
            int idx = tid + 256*i;
            int row = idx >> 5, c4 = idx & 31;
            *(float4*)&Bs[row*132 + c4*4] = *(const float4*)(Bp + (m0+row)*512 + hc + c4*4);
        }
        if (tid < 128) W2s[tid] = W2[hc + tid];
        __syncthreads();

        #pragma unroll 4
        for (int h4 = 0; h4 < 32; ++h4) {
            float4 a0 = *(const float4*)&As[ty*132 + 4*h4];
            float4 a1 = *(const float4*)&As[(ty+16)*132 + 4*h4];
            float4 bv = *(const float4*)&Bs[tx*132 + 4*h4];
            float4 w4 = *(const float4*)&W2s[4*h4];
            float aa0[4] = {a0.x,a0.y,a0.z,a0.w};
            float aa1[4] = {a1.x,a1.y,a1.z,a1.w};
            float bb[4]  = {bv.x,bv.y,bv.z,bv.w};
            float ww[4]  = {w4.x,w4.y,w4.z,w4.w};
            #pragma unroll
            for (int qi = 0; qi < 4; ++qi) {
                float r0v = frcp(1.f + fexp2(aa0[qi] + bb[qi]));
                float r1v = frcp(1.f + fexp2(aa1[qi] + bb[qi]));
                acc0 = fmaf(ww[qi], fmaf(-2.f, r0v, 1.f), acc0);
                acc1 = fmaf(ww[qi], fmaf(-2.f, r1v, 1.f), acc1);
            }
        }
        __syncthreads();
    }

    float b2s = b2p[0];
    int gm  = m0 + tx;
    int gn0 = n0 + ty;
    int gn1 = n0 + 16 + ty;
    float v0 = acc0 + b2s; if (gn0 == gm) v0 = 0.f;
    float v1 = acc1 + b2s; if (gn1 == gm) v1 = 0.f;
    S[gn0*512 + gm] = v0;
    S[gn1*512 + gm] = v1;

    ps[ty][tx] = v0 + v1;
    __syncthreads();
    if (tid < 16) {
        float s = 0.f;
        #pragma unroll
        for (int k = 0; k < 16; ++k) s += ps[k][tid];
        atomicAdd(&csum[m0 + tid], s);
    }
}

// ---------------- row softmax of S[n][m]/csum[m] ----------------
__global__ __launch_bounds__(256) void softmax_kernel(const float* __restrict__ S,
                                                      const float* __restrict__ csum,
                                                      float* __restrict__ out)
{
    int n = blockIdx.x, tid = threadIdx.x;
    float v0 = S[n*512 + tid]       / csum[tid];
    float v1 = S[n*512 + tid + 256] / csum[tid + 256];

    __shared__ float rbuf[4], rbuf2[4];
    int wid = tid >> 6;

    float mx = fmaxf(v0, v1);
    #pragma unroll
    for (int off = 32; off; off >>= 1) mx = fmaxf(mx, __shfl_xor(mx, off, 64));
    if ((tid & 63) == 0) rbuf[wid] = mx;
    __syncthreads();
    mx = fmaxf(fmaxf(rbuf[0], rbuf[1]), fmaxf(rbuf[2], rbuf[3]));

    float e0 = fexp2((v0 - mx)*LOG2E);
    float e1 = fexp2((v1 - mx)*LOG2E);
    float sm = e0 + e1;
    #pragma unroll
    for (int off = 32; off; off >>= 1) sm += __shfl_xor(sm, off, 64);
    if ((tid & 63) == 0) rbuf2[wid] = sm;
    __syncthreads();
    sm = (rbuf2[0] + rbuf2[1]) + (rbuf2[2] + rbuf2[3]);

    float inv = 1.0f / sm;
    out[n*512 + tid]       = e0*inv;
    out[n*512 + tid + 256] = e1*inv;
}

extern "C" void kernel_launch(void* const* d_in, const int* in_sizes, int n_in,
                              void* d_out, int out_size, void* d_ws, size_t ws_size,
                              hipStream_t stream)
{
    const int*   wid  = (const int*)d_in[0];
    const int*   tgi  = (const int*)d_in[1];
    const float* wemb = (const float*)d_in[2];
    const float* temb = (const float*)d_in[3];
    const float* h0   = (const float*)d_in[4];
    const float* c0   = (const float*)d_in[5];
    const float* Wih0f=(const float*)d_in[6],  *Whh0f=(const float*)d_in[7],  *bih0f=(const float*)d_in[8],  *bhh0f=(const float*)d_in[9];
    const float* Wih0b=(const float*)d_in[10], *Whh0b=(const float*)d_in[11], *bih0b=(const float*)d_in[12], *bhh0b=(const float*)d_in[13];
    const float* Wih1f=(const float*)d_in[14], *Whh1f=(const float*)d_in[15], *bih1f=(const float*)d_in[16], *bhh1f=(const float*)d_in[17];
    const float* Wih1b=(const float*)d_in[18], *Whh1b=(const float*)d_in[19], *bih1b=(const float*)d_in[20], *bhh1b=(const float*)d_in[21];
    const float* W1   = (const float*)d_in[22];
    const float* b1   = (const float*)d_in[23];
    const float* W2   = (const float*)d_in[24];
    const float* b2   = (const float*)d_in[25];

    float* ws    = (float*)d_ws;
    float* h0cat = ws;              // [0, 131072)
    float* h1cat = ws + 131072;     // [131072, 262144)
    float* pA    = ws + 262144;     // [262144, 524288)
    float* pB    = ws + 524288;     // [524288, 786432)
    float* S     = ws;              // [0, 262144)  (h0cat/h1cat dead by score)
    float* csum  = ws + 786432;     // [786432, 786944)
    float* out   = (float*)d_out;

    gemm_l0<<<dim3(8,8,2), 256, 0, stream>>>(wid, tgi, wemb, temb,
                                             Wih0f, Wih0b, bih0f, bih0b, bhh0f, bhh0b,
                                             pA, pB, csum);
    lstm_kernel<<<2, 512, 0, stream>>>(pA, pB, Whh0f, Whh0b, h0, c0, h0cat, 0);

    gemm2<<<dim3(8,8,2), 256, 0, stream>>>(h0cat, 256, Wih1f, Wih1b, 256, 0,
                                           bih1f, bih1b, bhh1f, bhh1b,
                                           pA, pB, 256, 1.0f);
    lstm_kernel<<<2, 512, 0, stream>>>(pA, pB, Whh1f, Whh1b, h0, c0, h1cat, 1);

    gemm2<<<dim3(8,8,2), 256, 0, stream>>>(h1cat, 256, W1, W1, 512, 256,
                                           b1, nullptr, nullptr, nullptr,
                                           pA, pB, 256, TWO_LOG2E);

    score_kernel<<<dim3(32,16), 256, 0, stream>>>(pA, pB, W2, b2, S, csum);
    softmax_kernel<<<512, 256, 0, stream>>>(S, csum, out);
}

// Round 4
// 637.566 us; speedup vs baseline: 1.1781x; 1.1781x over previous
//
#include <hip/hip_runtime.h>

#define LOG2E 1.4426950408889634f
#define TWO_LOG2E 2.8853900817779268f

#if __has_builtin(__builtin_amdgcn_exp2f)
__device__ __forceinline__ float fexp2(float x){ return __builtin_amdgcn_exp2f(x); }
#else
__device__ __forceinline__ float fexp2(float x){ return exp2f(x); }
#endif
#if __has_builtin(__builtin_amdgcn_rcpf)
__device__ __forceinline__ float frcp(float x){ return __builtin_amdgcn_rcpf(x); }
#else
__device__ __forceinline__ float frcp(float x){ return 1.0f/(x); }
#endif

// DPP cross-lane move (full-rate VALU, no LDS pipe)
template<int CTRL>
__device__ __forceinline__ float dpp_f(float x) {
    return __int_as_float(__builtin_amdgcn_update_dpp(0, __float_as_int(x), CTRL, 0xF, 0xF, true));
}
#define DPP_BC0   0x00   // quad bcast lane0
#define DPP_BC1   0x55
#define DPP_BC2   0xAA
#define DPP_BC3   0xFF

typedef unsigned int u32;
typedef _Float16 f16x8 __attribute__((ext_vector_type(8)));
typedef float    f32x4 __attribute__((ext_vector_type(4)));

// ---- layer-0 pre GEMM with fused embedding gather + csum zeroing ----------
__global__ __launch_bounds__(256) void gemm_l0(
    const int* __restrict__ wid, const int* __restrict__ tgi,
    const float* __restrict__ wemb, const float* __restrict__ temb,
    const float* __restrict__ Wa, const float* __restrict__ Wb,
    const float* __restrict__ b1a, const float* __restrict__ b1b,
    const float* __restrict__ b2a, const float* __restrict__ b2b,
    float* __restrict__ Ca, float* __restrict__ Cb,
    float* __restrict__ csum)
{
    int tid = threadIdx.x;
    if (blockIdx.x == 0 && blockIdx.y == 0 && blockIdx.z == 0) {
        csum[tid] = 0.f; csum[tid + 256] = 0.f;   // zero for score's atomics
    }
    int z = blockIdx.z;
    const float* W   = z ? Wb  : Wa;
    const float* bb1 = z ? b1b : b1a;
    const float* bb2 = z ? b2b : b2a;
    float* C = z ? Cb : Ca;

    __shared__ float Xs[64*33];
    __shared__ float Ws[64*33];
    int tx = tid & 15, ty = tid >> 4;
    int n0 = blockIdx.y*64, r0 = blockIdx.x*64;
    float acc[4][4] = {};

    for (int k0 = 0; k0 < 128; k0 += 32) {
        #pragma unroll
        for (int i = 0; i < 2; ++i) {
            int idx = tid + 256*i;
            int row = idx >> 3, c4 = idx & 7;
            int k = k0 + c4*4;
            int rg = n0 + row;
            float4 vx = (k < 100) ? *(const float4*)(wemb + wid[rg]*100 + k)
                                  : *(const float4*)(temb + tgi[rg]*28 + (k-100));
            float4 vw = *(const float4*)(W + (r0+row)*128 + k0 + c4*4);
            Xs[row*33 + c4*4+0]=vx.x; Xs[row*33 + c4*4+1]=vx.y; Xs[row*33 + c4*4+2]=vx.z; Xs[row*33 + c4*4+3]=vx.w;
            Ws[row*33 + c4*4+0]=vw.x; Ws[row*33 + c4*4+1]=vw.y; Ws[row*33 + c4*4+2]=vw.z; Ws[row*33 + c4*4+3]=vw.w;
        }
        __syncthreads();
        #pragma unroll 8
        for (int kk = 0; kk < 32; ++kk) {
            float a[4], b[4];
            #pragma unroll
            for (int i = 0; i < 4; ++i) a[i] = Xs[(4*ty+i)*33 + kk];
            #pragma unroll
            for (int j = 0; j < 4; ++j) b[j] = Ws[(4*tx+j)*33 + kk];
            #pragma unroll
            for (int i = 0; i < 4; ++i)
                #pragma unroll
                for (int j = 0; j < 4; ++j)
                    acc[i][j] = fmaf(a[i], b[j], acc[i][j]);
        }
        __syncthreads();
    }
    #pragma unroll
    for (int i = 0; i < 4; ++i)
        #pragma unroll
        for (int j = 0; j < 4; ++j) {
            int r = r0 + 4*tx + j;
            C[(n0 + 4*ty + i)*512 + r] = acc[i][j] + bb1[r] + bb2[r];
        }
}

// ------------- generic fused-pair GEMM: C[n][r] = scale*(X·W^T + b1 + b2) ----
__global__ __launch_bounds__(256) void gemm2(
    const float* __restrict__ X, int ldx,
    const float* __restrict__ Wa, const float* __restrict__ Wb, int ldw, int woffb,
    const float* __restrict__ b1a, const float* __restrict__ b1b,
    const float* __restrict__ b2a, const float* __restrict__ b2b,
    float* __restrict__ Ca, float* __restrict__ Cb,
    int K, float scale)
{
    int z = blockIdx.z;
    const float* W  = z ? Wb  : Wa;
    const float* bb1 = z ? b1b : b1a;
    const float* bb2 = z ? b2b : b2a;
    float* C = z ? Cb : Ca;
    int woff = z ? woffb : 0;

    __shared__ float Xs[64*33];
    __shared__ float Ws[64*33];
    int tid = threadIdx.x;
    int tx = tid & 15, ty = tid >> 4;
    int n0 = blockIdx.y*64, r0 = blockIdx.x*64;
    float acc[4][4] = {};

    for (int k0 = 0; k0 < K; k0 += 32) {
        #pragma unroll
        for (int i = 0; i < 2; ++i) {
            int idx = tid + 256*i;
            int row = idx >> 3, c4 = idx & 7;
            float4 vx = *(const float4*)(X + (n0+row)*ldx + k0 + c4*4);
            float4 vw = *(const float4*)(W + (r0+row)*ldw + woff + k0 + c4*4);
            Xs[row*33 + c4*4+0]=vx.x; Xs[row*33 + c4*4+1]=vx.y; Xs[row*33 + c4*4+2]=vx.z; Xs[row*33 + c4*4+3]=vx.w;
            Ws[row*33 + c4*4+0]=vw.x; Ws[row*33 + c4*4+1]=vw.y; Ws[row*33 + c4*4+2]=vw.z; Ws[row*33 + c4*4+3]=vw.w;
        }
        __syncthreads();
        #pragma unroll 8
        for (int kk = 0; kk < 32; ++kk) {
            float a[4], b[4];
            #pragma unroll
            for (int i = 0; i < 4; ++i) a[i] = Xs[(4*ty+i)*33 + kk];
            #pragma unroll
            for (int j = 0; j < 4; ++j) b[j] = Ws[(4*tx+j)*33 + kk];
            #pragma unroll
            for (int i = 0; i < 4; ++i)
                #pragma unroll
                for (int j = 0; j < 4; ++j)
                    acc[i][j] = fmaf(a[i], b[j], acc[i][j]);
        }
        __syncthreads();
    }
    #pragma unroll
    for (int i = 0; i < 4; ++i)
        #pragma unroll
        for (int j = 0; j < 4; ++j) {
            int r = r0 + 4*tx + j;
            float v = acc[i][j];
            if (bb1) v += bb1[r];
            if (bb2) v += bb2[r];
            C[(n0 + 4*ty + i)*512 + r] = v*scale;
        }
}

// ---------------- LSTM: 512 threads, MFMA recurrent matvec ------------------
// Per direction-step: g = Whh(512x128) * h(128) via v_mfma_f32_16x16x32_f16,
// h broadcast into all 16 B-columns (B-frag = one 16B broadcast LDS read per
// K-chunk). Whh A-frags preloaded in VGPRs (64 regs). Wave w owns cells
// [16w,16w+16): 4 gate-tiles x 4 K-chunks = 16 MFMAs/step on the MFMA pipe
// (VALU MAC was the floor at ~512cy/SIMD/step through R0-R3; fp16 VALU ops
// are half-rate on gfx950 per R3).
// D layout (m89): col=lane&15, row=(lane>>4)*4+reg; B cols identical so lane
// l holds gates g of cells 16w+4*(l>>4)+r. Assignment: quad of lanes
// j=l&15: gate q=j&3, cell-sub rsel=j>>2 -> 15 cndmask select, then the
// verified quad-DPP broadcast gate math (unchanged from R2).
__global__ __launch_bounds__(512, 2) void lstm_kernel(
    const float* __restrict__ preF, const float* __restrict__ preB,
    const float* __restrict__ WhhF, const float* __restrict__ WhhB,
    const float* __restrict__ h0, const float* __restrict__ c0,
    float* __restrict__ hout, int layer)
{
    const int dir = blockIdx.x;
    const int tid = threadIdx.x;
    const int l   = tid & 63;
    const int w   = tid >> 6;      // wave 0..7: cells [16w, 16w+16)
    const int j   = l & 15;
    const int kb  = l >> 4;        // 0..3 (K-block lane group / D row-block)
    const int q   = j & 3;         // gate handled by this lane
    const int rsel= j >> 2;        // cell-sub within row-block
    const int cell= 16*w + 4*kb + rsel;   // 0..127, one cell per quad
    const float* Whh  = dir ? WhhB : WhhF;
    const float* preD = dir ? preB : preF;

    // ---- preload A-frags: afr[g][kc] = Whh[(g<<7)+16w+j][32kc+8kb .. +7] ----
    // (A layout: lane l -> row l&15, k = 8*(l>>4)+e)
    f16x8 afr[4][4];
    #pragma unroll
    for (int g = 0; g < 4; ++g) {
        const float* wr = Whh + ((g << 7) + 16*w + j)*128 + (kb << 3);
        #pragma unroll
        for (int kc = 0; kc < 4; ++kc) {
            float4 u = *(const float4*)(wr + (kc << 5));
            float4 v = *(const float4*)(wr + (kc << 5) + 4);
            f16x8 a;
            a[0]=(_Float16)u.x; a[1]=(_Float16)u.y; a[2]=(_Float16)u.z; a[3]=(_Float16)u.w;
            a[4]=(_Float16)v.x; a[5]=(_Float16)v.y; a[6]=(_Float16)v.z; a[7]=(_Float16)v.w;
            afr[g][kc] = a;
        }
    }

    __shared__ __align__(16) _Float16 hbuf[2][128];   // fp16 h ping-pong

    const float* h0d = h0 + (2*layer + dir)*128;
    const float* c0d = c0 + (2*layer + dir)*128;
    float c = c0d[cell];
    if (tid < 128) hbuf[0][tid] = (_Float16)h0d[tid];

    const float sc = (q == 2) ? -TWO_LOG2E : -LOG2E;   // gate 2: sigm(2*gg)
    const int prow = (q << 7) + cell;
    const int t0 = dir ? 511 : 0;
    const int dt = dir ? -1 : 1;
    const int pstep = dt*512;
    const int hstep = dt*256;

    // pointer-walking; the one-past-the-end prefetch on the last step lands
    // in the adjacent workspace region (pA<->pB) — in bounds, value unused.
    const float* pptr = preD + t0*512 + prow;
    float*       hptr = hout + t0*256 + dir*128 + cell;

    const f32x4 zacc = {0.f, 0.f, 0.f, 0.f};

    float pcur = *pptr;
    __syncthreads();

    #pragma unroll 2
    for (int s = 0; s < 512; ++s) {
        pptr += pstep;
        float pnext = *pptr;           // prefetch one step ahead

        const int p = s & 1;
        // B-frags: broadcast reads, frag kc = h[32kc + 8kb .. +7]
        const uint4* h4 = (const uint4*)hbuf[p];
        f16x8 bf[4];
        #pragma unroll
        for (int kc = 0; kc < 4; ++kc)
            bf[kc] = __builtin_bit_cast(f16x8, h4[4*kc + kb]);

        // 4 gate-tiles x 4 K-chunks, 4-way interleaved chains
        f32x4 ac0 = __builtin_amdgcn_mfma_f32_16x16x32_f16(afr[0][0], bf[0], zacc, 0,0,0);
        f32x4 ac1 = __builtin_amdgcn_mfma_f32_16x16x32_f16(afr[1][0], bf[0], zacc, 0,0,0);
        f32x4 ac2 = __builtin_amdgcn_mfma_f32_16x16x32_f16(afr[2][0], bf[0], zacc, 0,0,0);
        f32x4 ac3 = __builtin_amdgcn_mfma_f32_16x16x32_f16(afr[3][0], bf[0], zacc, 0,0,0);
        #pragma unroll
        for (int kc = 1; kc < 4; ++kc) {
            ac0 = __builtin_amdgcn_mfma_f32_16x16x32_f16(afr[0][kc], bf[kc], ac0, 0,0,0);
            ac1 = __builtin_amdgcn_mfma_f32_16x16x32_f16(afr[1][kc], bf[kc], ac1, 0,0,0);
            ac2 = __builtin_amdgcn_mfma_f32_16x16x32_f16(afr[2][kc], bf[kc], ac2, 0,0,0);
            ac3 = __builtin_amdgcn_mfma_f32_16x16x32_f16(afr[3][kc], bf[kc], ac3, 0,0,0);
        }

        // V = D[gate q][reg rsel]  (15 cndmask; q,rsel loop-invariant masks)
        float x0 = (rsel & 2) ? ((rsel & 1) ? ac0[3] : ac0[2]) : ((rsel & 1) ? ac0[1] : ac0[0]);
        float x1 = (rsel & 2) ? ((rsel & 1) ? ac1[3] : ac1[2]) : ((rsel & 1) ? ac1[1] : ac1[0]);
        float x2 = (rsel & 2) ? ((rsel & 1) ? ac2[3] : ac2[2]) : ((rsel & 1) ? ac2[1] : ac2[0]);
        float x3 = (rsel & 2) ? ((rsel & 1) ? ac3[3] : ac3[2]) : ((rsel & 1) ? ac3[1] : ac3[0]);
        float v01 = (q & 1) ? x1 : x0;
        float v23 = (q & 1) ? x3 : x2;
        float V   = (q & 2) ? v23 : v01;

        float xg  = (V + pcur) * sc;
        float sv  = frcp(1.f + fexp2(xg));

        // share the four gates within the quad (lanes 4m..4m+3 = gates 0..3)
        float vi = dpp_f<DPP_BC0>(sv);
        float vf = dpp_f<DPP_BC1>(sv);
        float vg = dpp_f<DPP_BC2>(sv);
        float vo = dpp_f<DPP_BC3>(sv);

        float tg = fmaf(2.f, vg, -1.f);           // tanh(gg)
        c = fmaf(vf, c, vi*tg);
        float th = fmaf(-2.f, frcp(1.f + fexp2(TWO_LOG2E*c)), 1.f);  // tanh(c)
        float h  = vo * th;

        if (q == 1) hbuf[p ^ 1][cell] = (_Float16)h;
        if (q == 2) *hptr = h;
        hptr += hstep;
        // LDS-only barrier: do NOT drain vmcnt (hout store + pre prefetch
        // retire via the in-order vmcnt queue one step later, off-path).
        asm volatile("s_waitcnt lgkmcnt(0)\n\ts_barrier" ::: "memory");
        pcur = pnext;
    }
}

// --------- score: S[n][m] = sum_h w2[h]*tanh(A+B+b1) + b2, diag=0 -----------
__global__ __launch_bounds__(256) void score_kernel(
    const float* __restrict__ Ap, const float* __restrict__ Bp,
    const float* __restrict__ W2, const float* __restrict__ b2p,
    float* __restrict__ S, float* __restrict__ csum)
{
    __shared__ __align__(16) float As[32*132];
    __shared__ __align__(16) float Bs[16*132];
    __shared__ __align__(16) float W2s[128];
    __shared__ float ps[16][17];
    int tid = threadIdx.x;
    int tx = tid & 15, ty = tid >> 4;
    int m0 = blockIdx.x*16, n0 = blockIdx.y*32;
    float acc0 = 0.f, acc1 = 0.f;

    for (int hc = 0; hc < 512; hc += 128) {
        #pragma unroll
        for (int i = 0; i < 4; ++i) {
            int idx = tid + 256*i;
            int row = idx >> 5, c4 = idx & 31;
            *(float4*)&As[row*132 + c4*4] = *(const float4*)(Ap + (n0+row)*512 + hc + c4*4);
        }
        #pragma unroll
        for (int i = 0; i < 2; ++i) {
            int idx = tid + 256*i;
            int row = idx >> 5, c4 = idx & 31;
            *(float4*)&Bs[row*132 + c4*4] = *(const float4*)(Bp + (m0+row)*512 + hc + c4*4);
        }
        if (tid < 128) W2s[tid] = W2[hc + tid];
        __syncthreads();

        #pragma unroll 4
        for (int h4 = 0; h4 < 32; ++h4) {
            float4 a0 = *(const float4*)&As[ty*132 + 4*h4];
            float4 a1 = *(const float4*)&As[(ty+16)*132 + 4*h4];
            float4 bv = *(const float4*)&Bs[tx*132 + 4*h4];
            float4 w4 = *(const float4*)&W2s[4*h4];
            float aa0[4] = {a0.x,a0.y,a0.z,a0.w};
            float aa1[4] = {a1.x,a1.y,a1.z,a1.w};
            float bb[4]  = {bv.x,bv.y,bv.z,bv.w};
            float ww[4]  = {w4.x,w4.y,w4.z,w4.w};
            #pragma unroll
            for (int qi = 0; qi < 4; ++qi) {
                float r0v = frcp(1.f + fexp2(aa0[qi] + bb[qi]));
                float r1v = frcp(1.f + fexp2(aa1[qi] + bb[qi]));
                acc0 = fmaf(ww[qi], fmaf(-2.f, r0v, 1.f), acc0);
                acc1 = fmaf(ww[qi], fmaf(-2.f, r1v, 1.f), acc1);
            }
        }
        __syncthreads();
    }

    float b2s = b2p[0];
    int gm  = m0 + tx;
    int gn0 = n0 + ty;
    int gn1 = n0 + 16 + ty;
    float v0 = acc0 + b2s; if (gn0 == gm) v0 = 0.f;
    float v1 = acc1 + b2s; if (gn1 == gm) v1 = 0.f;
    S[gn0*512 + gm] = v0;
    S[gn1*512 + gm] = v1;

    ps[ty][tx] = v0 + v1;
    __syncthreads();
    if (tid < 16) {
        float s = 0.f;
        #pragma unroll
        for (int k = 0; k < 16; ++k) s += ps[k][tid];
        atomicAdd(&csum[m0 + tid], s);
    }
}

// ---------------- row softmax of S[n][m]/csum[m] ----------------
__global__ __launch_bounds__(256) void softmax_kernel(const float* __restrict__ S,
                                                      const float* __restrict__ csum,
                                                      float* __restrict__ out)
{
    int n = blockIdx.x, tid = threadIdx.x;
    float v0 = S[n*512 + tid]       / csum[tid];
    float v1 = S[n*512 + tid + 256] / csum[tid + 256];

    __shared__ float rbuf[4], rbuf2[4];
    int wid = tid >> 6;

    float mx = fmaxf(v0, v1);
    #pragma unroll
    for (int off = 32; off; off >>= 1) mx = fmaxf(mx, __shfl_xor(mx, off, 64));
    if ((tid & 63) == 0) rbuf[wid] = mx;
    __syncthreads();
    mx = fmaxf(fmaxf(rbuf[0], rbuf[1]), fmaxf(rbuf[2], rbuf[3]));

    float e0 = fexp2((v0 - mx)*LOG2E);
    float e1 = fexp2((v1 - mx)*LOG2E);
    float sm = e0 + e1;
    #pragma unroll
    for (int off = 32; off; off >>= 1) sm += __shfl_xor(sm, off, 64);
    if ((tid & 63) == 0) rbuf2[wid] = sm;
    __syncthreads();
    sm = (rbuf2[0] + rbuf2[1]) + (rbuf2[2] + rbuf2[3]);

    float inv = 1.0f / sm;
    out[n*512 + tid]       = e0*inv;
    out[n*512 + tid + 256] = e1*inv;
}

extern "C" void kernel_launch(void* const* d_in, const int* in_sizes, int n_in,
                              void* d_out, int out_size, void* d_ws, size_t ws_size,
                              hipStream_t stream)
{
    const int*   wid  = (const int*)d_in[0];
    const int*   tgi  = (const int*)d_in[1];
    const float* wemb = (const float*)d_in[2];
    const float* temb = (const float*)d_in[3];
    const float* h0   = (const float*)d_in[4];
    const float* c0   = (const float*)d_in[5];
    const float* Wih0f=(const float*)d_in[6],  *Whh0f=(const float*)d_in[7],  *bih0f=(const float*)d_in[8],  *bhh0f=(const float*)d_in[9];
    const float* Wih0b=(const float*)d_in[10], *Whh0b=(const float*)d_in[11], *bih0b=(const float*)d_in[12], *bhh0b=(const float*)d_in[13];
    const float* Wih1f=(const float*)d_in[14], *Whh1f=(const float*)d_in[15], *bih1f=(const float*)d_in[16], *bhh1f=(const float*)d_in[17];
    const float* Wih1b=(const float*)d_in[18], *Whh1b=(const float*)d_in[19], *bih1b=(const float*)d_in[20], *bhh1b=(const float*)d_in[21];
    const float* W1   = (const float*)d_in[22];
    const float* b1   = (const float*)d_in[23];
    const float* W2   = (const float*)d_in[24];
    const float* b2   = (const float*)d_in[25];

    float* ws    = (float*)d_ws;
    float* h0cat = ws;              // [0, 131072)
    float* h1cat = ws + 131072;     // [131072, 262144)
    float* pA    = ws + 262144;     // [262144, 524288)
    float* pB    = ws + 524288;     // [524288, 786432)
    float* S     = ws;              // [0, 262144)  (h0cat/h1cat dead by score)
    float* csum  = ws + 786432;     // [786432, 786944)
    float* out   = (float*)d_out;

    gemm_l0<<<dim3(8,8,2), 256, 0, stream>>>(wid, tgi, wemb, temb,
                                             Wih0f, Wih0b, bih0f, bih0b, bhh0f, bhh0b,
                                             pA, pB, csum);
    lstm_kernel<<<2, 512, 0, stream>>>(pA, pB, Whh0f, Whh0b, h0, c0, h0cat, 0);

    gemm2<<<dim3(8,8,2), 256, 0, stream>>>(h0cat, 256, Wih1f, Wih1b, 256, 0,
                                           bih1f, bih1b, bhh1f, bhh1b,
                                           pA, pB, 256, 1.0f);
    lstm_kernel<<<2, 512, 0, stream>>>(pA, pB, Whh1f, Whh1b, h0, c0, h1cat, 1);

    gemm2<<<dim3(8,8,2), 256, 0, stream>>>(h1cat, 256, W1, W1, 512, 256,
                                           b1, nullptr, nullptr, nullptr,
                                           pA, pB, 256, TWO_LOG2E);

    score_kernel<<<dim3(32,16), 256, 0, stream>>>(pA, pB, W2, b2, S, csum);
    softmax_kernel<<<512, 256, 0, stream>>>(S, csum, out);
}